// Round 7
// baseline (162.732 us; speedup 1.0000x reference)
//
#include <hip/hip_runtime.h>

#define N_Q 4096
#define M_T 16384
#define D_ 32
#define OUT_ 16
#define EPS_ 1e-6f
#define NC_ 128              // M-chunks (one block column each)
#define MB_ (M_T / NC_)      // 128 points per chunk == one LDS tile
#define QPT 2                // queries per thread in phase 1
#define NKEY 8               // keys kept per (query, chunk)
#define NCAND 12             // candidates merged+rescored in phase 2

// ---------------------------------------------------------------------------
// Phase 0: xqs = x / exp(w), xts = train_x / exp(w), plus row norms.
// ---------------------------------------------------------------------------
__global__ __launch_bounds__(256) void p0_scale(const float* __restrict__ x,
                                                const float* __restrict__ tx,
                                                const float* __restrict__ wts,
                                                float* __restrict__ xqs,
                                                float* __restrict__ xts,
                                                float* __restrict__ xqn,
                                                float* __restrict__ xtn) {
  int wid  = (blockIdx.x * blockDim.x + threadIdx.x) >> 6;
  int lane = threadIdx.x & 63;
  int row  = wid * 8 + (lane >> 3);
  int d0   = (lane & 7) * 4;
  if (row >= N_Q + M_T) return;
  const float* src; float* dst; float* ndst; int ri;
  if (row < N_Q) { src = x;  dst = xqs; ndst = xqn; ri = row; }
  else           { src = tx; dst = xts; ndst = xtn; ri = row - N_Q; }
  float4 v = *(const float4*)(src + (size_t)ri * D_ + d0);
  float s0 = expf(wts[d0 + 0]);
  float s1 = expf(wts[d0 + 1]);
  float s2 = expf(wts[d0 + 2]);
  float s3 = expf(wts[d0 + 3]);
  v.x /= s0; v.y /= s1; v.z /= s2; v.w /= s3;
  *(float4*)(dst + (size_t)ri * D_ + d0) = v;
  float nrm = v.x * v.x + v.y * v.y + v.z * v.z + v.w * v.w;
  nrm += __shfl_xor(nrm, 1);
  nrm += __shfl_xor(nrm, 2);
  nrm += __shfl_xor(nrm, 4);
  if ((lane & 7) == 0) ndst[ri] = nrm;
}

// ---------------------------------------------------------------------------
// Exact (value,index) sorted-ascending top-5 insert, static indices only.
// ---------------------------------------------------------------------------
__device__ __forceinline__ void insert5(float (&s)[5], int (&id)[5], float v, int vi) {
  float cs = v; int ci = vi;
#pragma unroll
  for (int k = 0; k < 5; ++k) {
    bool lt   = cs < s[k];
    float ts  = s[k]; int ti = id[k];
    s[k]  = lt ? cs : ts;
    id[k] = lt ? ci : ti;
    cs    = lt ? ts : cs;
    ci    = lt ? ti : ci;
  }
}

// ---------------------------------------------------------------------------
// Phase 1: grid (NC_ chunks, 8 query-groups), 256 threads, QPT queries/thread.
// Branchless key selection: key = (bits(max(sq,0)) & 0xFFFFC000) | global_idx.
// Query tile PINNED in VGPRs via empty asm (round 5: VGPR=68 proved the
// compiler was rematerializing the global loads inside the j-loop -> ~2x VALU).
// pkey chunk-major: each block writes one contiguous 16KB region (coalesced).
// ---------------------------------------------------------------------------
__global__ __launch_bounds__(256, 1) void p1_topk(const float* __restrict__ xqs,
                                                  const float* __restrict__ xqn,
                                                  const float* __restrict__ xts,
                                                  const float* __restrict__ xtn,
                                                  unsigned int* __restrict__ pkey) {
  __shared__ float sxt[MB_ * D_];
  __shared__ float sxtn[MB_];
  const int chunk = blockIdx.x;
  const int t     = threadIdx.x;
  const int q0    = blockIdx.y * (256 * QPT) + t * QPT;

  {
    const float4* gsrc = (const float4*)(xts + (size_t)chunk * MB_ * D_);
#pragma unroll
    for (int c = 0; c < 4; ++c) ((float4*)sxt)[t + c * 256] = gsrc[t + c * 256];
    if (t < MB_) sxtn[t] = xtn[chunk * MB_ + t];
  }

  float xq[QPT][32]; float qn[QPT];
#pragma unroll
  for (int q = 0; q < QPT; ++q) {
#pragma unroll
    for (int c = 0; c < 8; ++c) {
      float4 v = *(const float4*)(xqs + (size_t)(q0 + q) * D_ + c * 4);
      xq[q][c * 4 + 0] = v.x; xq[q][c * 4 + 1] = v.y;
      xq[q][c * 4 + 2] = v.z; xq[q][c * 4 + 3] = v.w;
    }
    qn[q] = xqn[q0 + q];
  }

  // Pin the query tile in VGPRs: the asm "writes" each value, so the compiler
  // cannot rematerialize it from the global load inside the j-loop.
#pragma unroll
  for (int q = 0; q < QPT; ++q) {
#pragma unroll
    for (int i = 0; i < 32; ++i) asm volatile("" : "+v"(xq[q][i]));
    asm volatile("" : "+v"(qn[q]));
  }

  unsigned int key[QPT][NKEY];
#pragma unroll
  for (int q = 0; q < QPT; ++q)
#pragma unroll
    for (int r = 0; r < NKEY; ++r) key[q][r] = 0xFFFFFFFFu;

  __syncthreads();

#pragma unroll 4
  for (int j = 0; j < MB_; ++j) {
    const float* p = sxt + j * D_;
    float d0 = 0.f, d1 = 0.f;
#pragma unroll
    for (int c = 0; c < 8; ++c) {
      float4 v = *(const float4*)(p + c * 4);   // wave-uniform -> LDS broadcast
      d0 = fmaf(xq[0][c * 4 + 0], v.x, d0);
      d0 = fmaf(xq[0][c * 4 + 1], v.y, d0);
      d0 = fmaf(xq[0][c * 4 + 2], v.z, d0);
      d0 = fmaf(xq[0][c * 4 + 3], v.w, d0);
      d1 = fmaf(xq[1][c * 4 + 0], v.x, d1);
      d1 = fmaf(xq[1][c * 4 + 1], v.y, d1);
      d1 = fmaf(xq[1][c * 4 + 2], v.z, d1);
      d1 = fmaf(xq[1][c * 4 + 3], v.w, d1);
    }
    const float tn = sxtn[j];
    const unsigned int gidx = (unsigned int)(chunk * MB_ + j);
    {
      float sq = fmaf(-2.0f, d0, qn[0] + tn);
      sq = fmaxf(sq, 0.0f);
      unsigned int k = (__float_as_uint(sq) & 0xFFFFC000u) | gidx;
#pragma unroll
      for (int r = 0; r < NKEY; ++r) {
        unsigned int lo = min(key[0][r], k);
        k = max(key[0][r], k);
        key[0][r] = lo;
      }
    }
    {
      float sq = fmaf(-2.0f, d1, qn[1] + tn);
      sq = fmaxf(sq, 0.0f);
      unsigned int k = (__float_as_uint(sq) & 0xFFFFC000u) | gidx;
#pragma unroll
      for (int r = 0; r < NKEY; ++r) {
        unsigned int lo = min(key[1][r], k);
        k = max(key[1][r], k);
        key[1][r] = lo;
      }
    }
  }

#pragma unroll
  for (int q = 0; q < QPT; ++q) {
    size_t base = ((size_t)chunk * N_Q + (q0 + q)) * NKEY;
    *(uint4*)(pkey + base)     = make_uint4(key[q][0], key[q][1], key[q][2], key[q][3]);
    *(uint4*)(pkey + base + 4) = make_uint4(key[q][4], key[q][5], key[q][6], key[q][7]);
  }
}

// ---------------------------------------------------------------------------
// Phase 2: one wave per query. Scan NC_*NKEY keys (16/lane), branchless merge
// to sorted top-12 via shfl_xor butterfly, exact fp32 rescore of the 12
// candidates, exact top-5, weights, gather train_y.
// ---------------------------------------------------------------------------
__global__ __launch_bounds__(256) void p2_merge(const unsigned int* __restrict__ pkey,
                                                const float* __restrict__ xqs,
                                                const float* __restrict__ xqn,
                                                const float* __restrict__ xts,
                                                const float* __restrict__ xtn,
                                                const float* __restrict__ ty,
                                                float* __restrict__ out) {
  const int q    = (blockIdx.x * blockDim.x + threadIdx.x) >> 6;
  const int lane = threadIdx.x & 63;
  if (q >= N_Q) return;

  unsigned int s[NCAND];
#pragma unroll
  for (int m = 0; m < NCAND; ++m) s[m] = 0xFFFFFFFFu;

#pragma unroll
  for (int i = 0; i < (NC_ * NKEY) / 64; ++i) {
    int c = lane + i * 64;
    unsigned int v = pkey[((size_t)(c >> 3) * N_Q + q) * NKEY + (c & 7)];
#pragma unroll
    for (int m = 0; m < NCAND; ++m) {
      unsigned int lo = min(s[m], v);
      v = max(s[m], v);
      s[m] = lo;
    }
  }

#pragma unroll
  for (int step = 1; step < 64; step <<= 1) {
    unsigned int ov[NCAND];
#pragma unroll
    for (int m = 0; m < NCAND; ++m) ov[m] = (unsigned int)__shfl_xor((int)s[m], step);
#pragma unroll
    for (int m = 0; m < NCAND; ++m) {
      unsigned int v = ov[m];
#pragma unroll
      for (int r = 0; r < NCAND; ++r) {
        unsigned int lo = min(s[r], v);
        v = max(s[r], v);
        s[r] = lo;
      }
    }
  }

  // lane m takes candidate m (static-index selection, no runtime reg indexing)
  unsigned int mykey = s[0];
#pragma unroll
  for (int m = 1; m < NCAND; ++m) mykey = (lane == m) ? s[m] : mykey;

  int   cidx = (int)(mykey & 0x3FFFu);
  float sqex = 3.0e38f;
  if (lane < NCAND) {
    float d = 0.f;
    const float* xr = xqs + (size_t)q * D_;
    const float* tr = xts + (size_t)cidx * D_;
#pragma unroll
    for (int c = 0; c < 8; ++c) {
      float4 a = *(const float4*)(xr + c * 4);
      float4 b = *(const float4*)(tr + c * 4);
      d = fmaf(a.x, b.x, d); d = fmaf(a.y, b.y, d);
      d = fmaf(a.z, b.z, d); d = fmaf(a.w, b.w, d);
    }
    sqex = fmaxf(xqn[q] + xtn[cidx] - 2.0f * d, 0.0f);
  }

  float s5[5]; int id5[5];
#pragma unroll
  for (int k = 0; k < 5; ++k) { s5[k] = 3.0e38f; id5[k] = 0; }
#pragma unroll
  for (int m = 0; m < NCAND; ++m) {
    float v  = __shfl(sqex, m);
    int   vi = __shfl(cidx, m);
    if (v < s5[4]) insert5(s5, id5, v, vi);   // wave-uniform branch
  }

  float dinv[5]; float wsum = 0.f;
#pragma unroll
  for (int k = 0; k < 5; ++k) {
    dinv[k] = 1.0f / sqrtf(s5[k] + EPS_);     // s5 already clamped >= 0
    wsum += dinv[k];
  }
  if (lane < OUT_) {
    float acc = 0.f;
#pragma unroll
    for (int k = 0; k < 5; ++k)
      acc = fmaf(dinv[k] / wsum, ty[(size_t)id5[k] * OUT_ + lane], acc);
    out[(size_t)q * OUT_ + lane] = acc;
  }
}

// ---------------------------------------------------------------------------
extern "C" void kernel_launch(void* const* d_in, const int* in_sizes, int n_in,
                              void* d_out, int out_size, void* d_ws, size_t ws_size,
                              hipStream_t stream) {
  const float* x   = (const float*)d_in[0];
  const float* tx  = (const float*)d_in[1];
  const float* ty  = (const float*)d_in[2];
  const float* wts = (const float*)d_in[3];
  float* out = (float*)d_out;

  char* ws = (char*)d_ws;
  size_t off = 0;
  float* xqs = (float*)(ws + off); off += (size_t)N_Q * D_ * 4;
  float* xts = (float*)(ws + off); off += (size_t)M_T * D_ * 4;
  float* xqn = (float*)(ws + off); off += (size_t)N_Q * 4;
  float* xtn = (float*)(ws + off); off += (size_t)M_T * 4;
  unsigned int* pkey = (unsigned int*)(ws + off);   // NC_*N_Q*NKEY*4 = 16.8MB

  p0_scale<<<dim3((N_Q + M_T) / 32), dim3(256), 0, stream>>>(x, tx, wts, xqs, xts, xqn, xtn);
  p1_topk<<<dim3(NC_, N_Q / (256 * QPT)), dim3(256), 0, stream>>>(xqs, xqn, xts, xtn, pkey);
  p2_merge<<<dim3(N_Q * 64 / 256), dim3(256), 0, stream>>>(pkey, xqs, xqn, xts, xtn, ty, out);
}

// Round 8
// 162.722 us; speedup vs baseline: 1.0001x; 1.0001x over previous
//
#include <hip/hip_runtime.h>

#define N_Q 4096
#define M_T 16384
#define D_ 32
#define OUT_ 16
#define EPS_ 1e-6f
#define NC_ 128              // M-chunks (one block column each)
#define MB_ (M_T / NC_)      // 128 points per chunk == one LDS tile
#define QPT 2                // queries per thread in phase 1
#define NKEY 6               // keys maintained per (query, chunk)
#define NSTO 8               // key slots stored (2 dummies -> uint4 stores)
#define NCAND 12             // candidates merged+rescored in phase 2
#define BIAS_ 128.0f         // key bias: v = tn + 128 - 2d > 0 always

// ---------------------------------------------------------------------------
// Phase 0: xqs = x / exp(w), xts = train_x / exp(w), plus row norms.
// ---------------------------------------------------------------------------
__global__ __launch_bounds__(256) void p0_scale(const float* __restrict__ x,
                                                const float* __restrict__ tx,
                                                const float* __restrict__ wts,
                                                float* __restrict__ xqs,
                                                float* __restrict__ xts,
                                                float* __restrict__ xqn,
                                                float* __restrict__ xtn) {
  int wid  = (blockIdx.x * blockDim.x + threadIdx.x) >> 6;
  int lane = threadIdx.x & 63;
  int row  = wid * 8 + (lane >> 3);
  int d0   = (lane & 7) * 4;
  if (row >= N_Q + M_T) return;
  const float* src; float* dst; float* ndst; int ri;
  if (row < N_Q) { src = x;  dst = xqs; ndst = xqn; ri = row; }
  else           { src = tx; dst = xts; ndst = xtn; ri = row - N_Q; }
  float4 v = *(const float4*)(src + (size_t)ri * D_ + d0);
  float s0 = expf(wts[d0 + 0]);
  float s1 = expf(wts[d0 + 1]);
  float s2 = expf(wts[d0 + 2]);
  float s3 = expf(wts[d0 + 3]);
  v.x /= s0; v.y /= s1; v.z /= s2; v.w /= s3;
  *(float4*)(dst + (size_t)ri * D_ + d0) = v;
  float nrm = v.x * v.x + v.y * v.y + v.z * v.z + v.w * v.w;
  nrm += __shfl_xor(nrm, 1);
  nrm += __shfl_xor(nrm, 2);
  nrm += __shfl_xor(nrm, 4);
  if ((lane & 7) == 0) ndst[ri] = nrm;
}

// ---------------------------------------------------------------------------
// Exact (value,index) sorted-ascending top-5 insert, static indices only.
// ---------------------------------------------------------------------------
__device__ __forceinline__ void insert5(float (&s)[5], int (&id)[5], float v, int vi) {
  float cs = v; int ci = vi;
#pragma unroll
  for (int k = 0; k < 5; ++k) {
    bool lt   = cs < s[k];
    float ts  = s[k]; int ti = id[k];
    s[k]  = lt ? cs : ts;
    id[k] = lt ? ci : ti;
    cs    = lt ? ts : cs;
    ci    = lt ? ti : ci;
  }
}

// ---------------------------------------------------------------------------
// Phase 1: grid (NC_ chunks, 8 query-groups), 256 threads, QPT queries/thread.
// key = (bits(tn + 128 - 2d) & 0xFFFFC000) | idx  (qn dropped: per-query
// constant; +128 bias keeps v > 0 so fp32 bits order as u32 with no clamp).
// Sorted top-6 via unconditional u32 min/max chain (12 ops, branchless).
// Query tile held in VGPRs via LOOP-CARRIED empty-asm pins: the asm redefines
// each element every iteration, so the compiler cannot sink the global loads
// into the loop (round 5/7: VGPR=68 -> per-iter re-gather was ~2x VALU).
// ---------------------------------------------------------------------------
__global__ __launch_bounds__(256, 1) void p1_topk(const float* __restrict__ xqs,
                                                  const float* __restrict__ xts,
                                                  const float* __restrict__ xtn,
                                                  unsigned int* __restrict__ pkey) {
  __shared__ float sxt[MB_ * D_];
  __shared__ float sxtn[MB_];
  const int chunk = blockIdx.x;
  const int t     = threadIdx.x;
  const int q0    = blockIdx.y * (256 * QPT) + t * QPT;

  {
    const float4* gsrc = (const float4*)(xts + (size_t)chunk * MB_ * D_);
#pragma unroll
    for (int c = 0; c < 4; ++c) ((float4*)sxt)[t + c * 256] = gsrc[t + c * 256];
    if (t < MB_) sxtn[t] = xtn[chunk * MB_ + t] + BIAS_;   // biased norm
  }

  float xq[QPT][32];
#pragma unroll
  for (int q = 0; q < QPT; ++q) {
#pragma unroll
    for (int c = 0; c < 8; ++c) {
      float4 v = *(const float4*)(xqs + (size_t)(q0 + q) * D_ + c * 4);
      xq[q][c * 4 + 0] = v.x; xq[q][c * 4 + 1] = v.y;
      xq[q][c * 4 + 2] = v.z; xq[q][c * 4 + 3] = v.w;
    }
  }

  unsigned int key[QPT][NKEY];
#pragma unroll
  for (int q = 0; q < QPT; ++q)
#pragma unroll
    for (int r = 0; r < NKEY; ++r) key[q][r] = 0xFFFFFFFFu;

  __syncthreads();

  for (int j = 0; j < MB_; ++j) {
    // Loop-carried register pin: zero instructions, forces VGPR residency.
#pragma unroll
    for (int q = 0; q < QPT; ++q)
#pragma unroll
      for (int i = 0; i < 32; ++i) asm volatile("" : "+v"(xq[q][i]));

    const float* p = sxt + j * D_;
    float d0 = 0.f, d1 = 0.f;
#pragma unroll
    for (int c = 0; c < 8; ++c) {
      float4 v = *(const float4*)(p + c * 4);   // wave-uniform -> LDS broadcast
      d0 = fmaf(xq[0][c * 4 + 0], v.x, d0);
      d0 = fmaf(xq[0][c * 4 + 1], v.y, d0);
      d0 = fmaf(xq[0][c * 4 + 2], v.z, d0);
      d0 = fmaf(xq[0][c * 4 + 3], v.w, d0);
      d1 = fmaf(xq[1][c * 4 + 0], v.x, d1);
      d1 = fmaf(xq[1][c * 4 + 1], v.y, d1);
      d1 = fmaf(xq[1][c * 4 + 2], v.z, d1);
      d1 = fmaf(xq[1][c * 4 + 3], v.w, d1);
    }
    const float tnB = sxtn[j];
    const unsigned int gidx = (unsigned int)(chunk * MB_ + j);
    {
      float v = fmaf(-2.0f, d0, tnB);           // > 0 by bias
      unsigned int k = (__float_as_uint(v) & 0xFFFFC000u) | gidx;
#pragma unroll
      for (int r = 0; r < NKEY; ++r) {
        unsigned int lo = min(key[0][r], k);
        k = max(key[0][r], k);
        key[0][r] = lo;
      }
    }
    {
      float v = fmaf(-2.0f, d1, tnB);
      unsigned int k = (__float_as_uint(v) & 0xFFFFC000u) | gidx;
#pragma unroll
      for (int r = 0; r < NKEY; ++r) {
        unsigned int lo = min(key[1][r], k);
        k = max(key[1][r], k);
        key[1][r] = lo;
      }
    }
  }

#pragma unroll
  for (int q = 0; q < QPT; ++q) {
    size_t base = ((size_t)chunk * N_Q + (q0 + q)) * NSTO;
    *(uint4*)(pkey + base)     = make_uint4(key[q][0], key[q][1], key[q][2], key[q][3]);
    *(uint4*)(pkey + base + 4) = make_uint4(key[q][4], key[q][5], 0xFFFFFFFFu, 0xFFFFFFFFu);
  }
}

// ---------------------------------------------------------------------------
// Phase 2: one wave per query. Scan NC_*NSTO keys (16/lane), branchless merge
// to sorted top-12 via shfl_xor butterfly, exact fp32 rescore of the 12
// candidates, exact top-5, weights, gather train_y.
// ---------------------------------------------------------------------------
__global__ __launch_bounds__(256) void p2_merge(const unsigned int* __restrict__ pkey,
                                                const float* __restrict__ xqs,
                                                const float* __restrict__ xqn,
                                                const float* __restrict__ xts,
                                                const float* __restrict__ xtn,
                                                const float* __restrict__ ty,
                                                float* __restrict__ out) {
  const int q    = (blockIdx.x * blockDim.x + threadIdx.x) >> 6;
  const int lane = threadIdx.x & 63;
  if (q >= N_Q) return;

  unsigned int s[NCAND];
#pragma unroll
  for (int m = 0; m < NCAND; ++m) s[m] = 0xFFFFFFFFu;

#pragma unroll
  for (int i = 0; i < (NC_ * NSTO) / 64; ++i) {
    int c = lane + i * 64;
    unsigned int v = pkey[((size_t)(c >> 3) * N_Q + q) * NSTO + (c & 7)];
#pragma unroll
    for (int m = 0; m < NCAND; ++m) {
      unsigned int lo = min(s[m], v);
      v = max(s[m], v);
      s[m] = lo;
    }
  }

#pragma unroll
  for (int step = 1; step < 64; step <<= 1) {
    unsigned int ov[NCAND];
#pragma unroll
    for (int m = 0; m < NCAND; ++m) ov[m] = (unsigned int)__shfl_xor((int)s[m], step);
#pragma unroll
    for (int m = 0; m < NCAND; ++m) {
      unsigned int v = ov[m];
#pragma unroll
      for (int r = 0; r < NCAND; ++r) {
        unsigned int lo = min(s[r], v);
        v = max(s[r], v);
        s[r] = lo;
      }
    }
  }

  // lane m takes candidate m (static-index selection, no runtime reg indexing)
  unsigned int mykey = s[0];
#pragma unroll
  for (int m = 1; m < NCAND; ++m) mykey = (lane == m) ? s[m] : mykey;

  int   cidx = (int)(mykey & 0x3FFFu);
  float sqex = 3.0e38f;
  if (lane < NCAND) {
    float d = 0.f;
    const float* xr = xqs + (size_t)q * D_;
    const float* tr = xts + (size_t)cidx * D_;
#pragma unroll
    for (int c = 0; c < 8; ++c) {
      float4 a = *(const float4*)(xr + c * 4);
      float4 b = *(const float4*)(tr + c * 4);
      d = fmaf(a.x, b.x, d); d = fmaf(a.y, b.y, d);
      d = fmaf(a.z, b.z, d); d = fmaf(a.w, b.w, d);
    }
    sqex = fmaxf(xqn[q] + xtn[cidx] - 2.0f * d, 0.0f);
  }

  float s5[5]; int id5[5];
#pragma unroll
  for (int k = 0; k < 5; ++k) { s5[k] = 3.0e38f; id5[k] = 0; }
#pragma unroll
  for (int m = 0; m < NCAND; ++m) {
    float v  = __shfl(sqex, m);
    int   vi = __shfl(cidx, m);
    if (v < s5[4]) insert5(s5, id5, v, vi);   // wave-uniform branch
  }

  float dinv[5]; float wsum = 0.f;
#pragma unroll
  for (int k = 0; k < 5; ++k) {
    dinv[k] = 1.0f / sqrtf(s5[k] + EPS_);     // s5 already clamped >= 0
    wsum += dinv[k];
  }
  if (lane < OUT_) {
    float acc = 0.f;
#pragma unroll
    for (int k = 0; k < 5; ++k)
      acc = fmaf(dinv[k] / wsum, ty[(size_t)id5[k] * OUT_ + lane], acc);
    out[(size_t)q * OUT_ + lane] = acc;
  }
}

// ---------------------------------------------------------------------------
extern "C" void kernel_launch(void* const* d_in, const int* in_sizes, int n_in,
                              void* d_out, int out_size, void* d_ws, size_t ws_size,
                              hipStream_t stream) {
  const float* x   = (const float*)d_in[0];
  const float* tx  = (const float*)d_in[1];
  const float* ty  = (const float*)d_in[2];
  const float* wts = (const float*)d_in[3];
  float* out = (float*)d_out;

  char* ws = (char*)d_ws;
  size_t off = 0;
  float* xqs = (float*)(ws + off); off += (size_t)N_Q * D_ * 4;
  float* xts = (float*)(ws + off); off += (size_t)M_T * D_ * 4;
  float* xqn = (float*)(ws + off); off += (size_t)N_Q * 4;
  float* xtn = (float*)(ws + off); off += (size_t)M_T * 4;
  unsigned int* pkey = (unsigned int*)(ws + off);   // NC_*N_Q*NSTO*4 = 16.8MB

  p0_scale<<<dim3((N_Q + M_T) / 32), dim3(256), 0, stream>>>(x, tx, wts, xqs, xts, xqn, xtn);
  p1_topk<<<dim3(NC_, N_Q / (256 * QPT)), dim3(256), 0, stream>>>(xqs, xts, xtn, pkey);
  p2_merge<<<dim3(N_Q * 64 / 256), dim3(256), 0, stream>>>(pkey, xqs, xqn, xts, xtn, ty, out);
}

// Round 9
// 134.548 us; speedup vs baseline: 1.2095x; 1.2094x over previous
//
#include <hip/hip_runtime.h>

#define N_Q 4096
#define M_T 16384
#define D_ 32
#define OUT_ 16
#define EPS_ 1e-6f
#define NCHUNK 16            // M-chunks (blockIdx.x)
#define CPTS (M_T / NCHUNK)  // 1024 points per chunk
#define TPTS 256             // points per LDS tile
#define NTILE (CPTS / TPTS)  // 4
#define NKEY 5               // per-lane keys (zero-loss for top-5)
#define NCAND 12             // merged+rescored in phase 2
#define BIAS_ 128.0f
#define KMASK 0xFFFFC000u

typedef short bf16x8 __attribute__((ext_vector_type(8)));
typedef float f32x4 __attribute__((ext_vector_type(4)));

static __device__ __forceinline__ unsigned short f2bf(float f) {
  unsigned int u = __float_as_uint(f);
  return (unsigned short)((u + 0x7FFFu + ((u >> 16) & 1u)) >> 16);  // RNE
}
static __device__ __forceinline__ float bf2f(unsigned short h) {
  return __uint_as_float(((unsigned int)h) << 16);
}

__device__ __forceinline__ void chain5(unsigned int (&a)[NKEY], unsigned int v) {
#pragma unroll
  for (int i = 0; i < NKEY; ++i) {
    unsigned int lo = min(a[i], v);
    v = max(a[i], v);
    a[i] = lo;
  }
}
__device__ __forceinline__ void chain12(unsigned int (&a)[NCAND], unsigned int v) {
#pragma unroll
  for (int i = 0; i < NCAND; ++i) {
    unsigned int lo = min(a[i], v);
    v = max(a[i], v);
    a[i] = lo;
  }
}
__device__ __forceinline__ void insert5f(float (&s)[5], int (&id)[5], float v, int vi) {
  float cs = v; int ci = vi;
#pragma unroll
  for (int k = 0; k < 5; ++k) {
    bool lt = cs < s[k];
    float ts = s[k]; int ti = id[k];
    s[k] = lt ? cs : ts;  id[k] = lt ? ci : ti;
    cs   = lt ? ts : cs;  ci    = lt ? ti : ci;
  }
}

// ---------------------------------------------------------------------------
// Phase 0: scale by exp(w), fp32 copies + norms + bf16 hi/lo in "tileT" layout:
// 16B chunk of row R, kgroup g lives at byte (R>>4)*1024 + g*256 + (R&15)*16.
// Thread = (row, kgroup): 4 threads/row, coalesced 32B fp32 loads.
// ---------------------------------------------------------------------------
__global__ __launch_bounds__(256) void p0_prep(const float* __restrict__ x,
                                               const float* __restrict__ tx,
                                               const float* __restrict__ wts,
                                               float* __restrict__ xqs,
                                               float* __restrict__ xts,
                                               float* __restrict__ xqn,
                                               float* __restrict__ xtn,
                                               unsigned short* __restrict__ xq_h,
                                               unsigned short* __restrict__ xq_l,
                                               unsigned short* __restrict__ xt_h,
                                               unsigned short* __restrict__ xt_l) {
  int gid = blockIdx.x * 256 + threadIdx.x;
  int row = gid >> 2;
  int g   = gid & 3;
  if (row >= N_Q + M_T) return;
  const float* src; float* dstf; unsigned short *dh, *dl; float* ndst; int ri;
  if (row < N_Q) { src = x;  dstf = xqs; dh = xq_h; dl = xq_l; ndst = xqn; ri = row; }
  else           { src = tx; dstf = xts; dh = xt_h; dl = xt_l; ndst = xtn; ri = row - N_Q; }
  float4 a = *(const float4*)(src + (size_t)ri * D_ + g * 8);
  float4 b = *(const float4*)(src + (size_t)ri * D_ + g * 8 + 4);
  float v[8] = {a.x, a.y, a.z, a.w, b.x, b.y, b.z, b.w};
  float nrm = 0.f;
  unsigned short hh[8], ll[8];
#pragma unroll
  for (int i = 0; i < 8; ++i) {
    float s = expf(wts[g * 8 + i]);
    v[i] /= s;
    nrm = fmaf(v[i], v[i], nrm);
    hh[i] = f2bf(v[i]);
    ll[i] = f2bf(v[i] - bf2f(hh[i]));
  }
  *(float4*)(dstf + (size_t)ri * D_ + g * 8)     = make_float4(v[0], v[1], v[2], v[3]);
  *(float4*)(dstf + (size_t)ri * D_ + g * 8 + 4) = make_float4(v[4], v[5], v[6], v[7]);
  nrm += __shfl_xor(nrm, 1);
  nrm += __shfl_xor(nrm, 2);
  if (g == 0) ndst[ri] = nrm;
  size_t ti = (size_t)(ri >> 4) * 512 + g * 128 + (ri & 15) * 8;  // ushort units
  uint4 hv, lv;
  hv.x = hh[0] | (hh[1] << 16); hv.y = hh[2] | (hh[3] << 16);
  hv.z = hh[4] | (hh[5] << 16); hv.w = hh[6] | (hh[7] << 16);
  lv.x = ll[0] | (ll[1] << 16); lv.y = ll[2] | (ll[3] << 16);
  lv.z = ll[4] | (ll[5] << 16); lv.w = ll[6] | (ll[7] << 16);
  *(uint4*)(dh + ti) = hv;
  *(uint4*)(dl + ti) = lv;
}

// ---------------------------------------------------------------------------
// Phase 1: MFMA distance + branchless packed-key top-5.
// Block = 4 waves x 32 queries = 128 queries, one M-chunk of 1024 points.
// Per 16-pt subtile: 2 ds_read_b128 (lane-linear, conflict-free), 6 MFMA
// (hi/lo split, 2 query-halves), 8 key-chain updates per lane.
// C layout (m89-verified): col(point)=lane&15, row(query)=(lane>>4)*4+r.
// Tail: 16-lane shfl_xor butterfly merge -> 5 keys per (query, chunk).
// ---------------------------------------------------------------------------
__global__ __launch_bounds__(256) void p1_topk(const unsigned short* __restrict__ xq_h,
                                               const unsigned short* __restrict__ xq_l,
                                               const unsigned short* __restrict__ xt_h,
                                               const unsigned short* __restrict__ xt_l,
                                               const float* __restrict__ xtn,
                                               unsigned int* __restrict__ pkey) {
  __shared__ unsigned short sh[TPTS * D_];   // 16KB hi tile (tileT order)
  __shared__ unsigned short sl[TPTS * D_];   // 16KB lo tile
  __shared__ float stn[TPTS];                // biased norms
  const int t = threadIdx.x;
  const int w = t >> 6, lane = t & 63;
  const int p = lane & 15, g = lane >> 4;
  const int chunk = blockIdx.x;
  const int qb = blockIdx.y * 128 + w * 32;

  // A-fragments: loop-invariant, 16 VGPRs total
  const size_t abase = (size_t)(qb >> 4) * 512 + g * 128 + p * 8;
  const bf16x8 ah0 = *(const bf16x8*)(xq_h + abase);
  const bf16x8 al0 = *(const bf16x8*)(xq_l + abase);
  const bf16x8 ah1 = *(const bf16x8*)(xq_h + abase + 512);
  const bf16x8 al1 = *(const bf16x8*)(xq_l + abase + 512);
  const f32x4 zero = {0.f, 0.f, 0.f, 0.f};

  unsigned int key0[4][NKEY], key1[4][NKEY];
#pragma unroll
  for (int r = 0; r < 4; ++r)
#pragma unroll
    for (int k = 0; k < NKEY; ++k) { key0[r][k] = 0xFFFFFFFFu; key1[r][k] = 0xFFFFFFFFu; }

  for (int tt = 0; tt < NTILE; ++tt) {
    const int pbase = chunk * CPTS + tt * TPTS;
    // reg-staged tile loads issued early (T14: hide under prior compute)
    uint4 vh[4], vl[4];
    const size_t gb = (size_t)(pbase >> 4) * 512;
#pragma unroll
    for (int c = 0; c < 4; ++c) {
      size_t o = gb + (size_t)(w * 4 + c) * 512 + lane * 8;
      vh[c] = *(const uint4*)(xt_h + o);
      vl[c] = *(const uint4*)(xt_l + o);
    }
    float tn1 = xtn[pbase + t] + BIAS_;
    __syncthreads();   // previous tile fully consumed
#pragma unroll
    for (int c = 0; c < 4; ++c) {
      *(uint4*)(sh + (w * 4 + c) * 512 + lane * 8) = vh[c];
      *(uint4*)(sl + (w * 4 + c) * 512 + lane * 8) = vl[c];
    }
    stn[t] = tn1;
    __syncthreads();

#pragma unroll 2
    for (int s = 0; s < 16; ++s) {
      const bf16x8 bh = *(const bf16x8*)(sh + s * 512 + lane * 8);
      const bf16x8 bl = *(const bf16x8*)(sl + s * 512 + lane * 8);
      const float tnB = stn[s * 16 + p];
      f32x4 acc0 = __builtin_amdgcn_mfma_f32_16x16x32_bf16(ah0, bl, zero, 0, 0, 0);
      acc0 = __builtin_amdgcn_mfma_f32_16x16x32_bf16(al0, bh, acc0, 0, 0, 0);
      acc0 = __builtin_amdgcn_mfma_f32_16x16x32_bf16(ah0, bh, acc0, 0, 0, 0);
      f32x4 acc1 = __builtin_amdgcn_mfma_f32_16x16x32_bf16(ah1, bl, zero, 0, 0, 0);
      acc1 = __builtin_amdgcn_mfma_f32_16x16x32_bf16(al1, bh, acc1, 0, 0, 0);
      acc1 = __builtin_amdgcn_mfma_f32_16x16x32_bf16(ah1, bh, acc1, 0, 0, 0);
      const unsigned int kor = (unsigned int)(pbase + s * 16 + p);
#pragma unroll
      for (int r = 0; r < 4; ++r) {
        float v0 = fmaf(-2.0f, acc0[r], tnB);          // > 0 by bias
        chain5(key0[r], (__float_as_uint(v0) & KMASK) | kor);
        float v1 = fmaf(-2.0f, acc1[r], tnB);
        chain5(key1[r], (__float_as_uint(v1) & KMASK) | kor);
      }
    }
  }

  // merge across the 16 lanes holding each query's columns, then write 5 keys
#define WRITE5(KARR, h)                                                        \
  {                                                                            \
    _Pragma("unroll") for (int r = 0; r < 4; ++r) {                            \
      _Pragma("unroll") for (int step = 1; step < 16; step <<= 1) {            \
        unsigned int ov[NKEY];                                                 \
        _Pragma("unroll") for (int k = 0; k < NKEY; ++k)                       \
            ov[k] = (unsigned int)__shfl_xor((int)KARR[r][k], step);           \
        _Pragma("unroll") for (int k = 0; k < NKEY; ++k) chain5(KARR[r], ov[k]); \
      }                                                                        \
      if (p < 5) {                                                             \
        unsigned int val = KARR[r][0];                                         \
        val = (p == 1) ? KARR[r][1] : val;                                     \
        val = (p == 2) ? KARR[r][2] : val;                                     \
        val = (p == 3) ? KARR[r][3] : val;                                     \
        val = (p == 4) ? KARR[r][4] : val;                                     \
        pkey[(size_t)(qb + (h)*16 + g * 4 + r) * (NCHUNK * 5) + chunk * 5 + p] = val; \
      }                                                                        \
    }                                                                          \
  }
  WRITE5(key0, 0)
  WRITE5(key1, 1)
#undef WRITE5
}

// ---------------------------------------------------------------------------
// Phase 2: one wave per query. 80 contiguous keys -> branchless top-12 via
// chain + shfl_xor butterfly, exact fp32 rescore of 12, exact top-5, output.
// ---------------------------------------------------------------------------
__global__ __launch_bounds__(256) void p2_merge(const unsigned int* __restrict__ pkey,
                                                const float* __restrict__ xqs,
                                                const float* __restrict__ xqn,
                                                const float* __restrict__ xts,
                                                const float* __restrict__ xtn,
                                                const float* __restrict__ ty,
                                                float* __restrict__ out) {
  const int q    = (blockIdx.x * blockDim.x + threadIdx.x) >> 6;
  const int lane = threadIdx.x & 63;
  if (q >= N_Q) return;
  const unsigned int* kb = pkey + (size_t)q * (NCHUNK * 5);

  unsigned int s[NCAND];
#pragma unroll
  for (int m = 0; m < NCAND; ++m) s[m] = 0xFFFFFFFFu;
  chain12(s, kb[lane]);
  unsigned int v2 = 0xFFFFFFFFu;
  if (lane < 16) v2 = kb[64 + lane];
  chain12(s, v2);

#pragma unroll
  for (int step = 1; step < 64; step <<= 1) {
    unsigned int ov[NCAND];
#pragma unroll
    for (int m = 0; m < NCAND; ++m) ov[m] = (unsigned int)__shfl_xor((int)s[m], step);
#pragma unroll
    for (int m = 0; m < NCAND; ++m) chain12(s, ov[m]);
  }

  unsigned int mykey = s[0];
#pragma unroll
  for (int m = 1; m < NCAND; ++m) mykey = (lane == m) ? s[m] : mykey;

  int   cidx = (int)(mykey & 0x3FFFu);
  float sqex = 3.0e38f;
  if (lane < NCAND) {
    float d = 0.f;
    const float* xr = xqs + (size_t)q * D_;
    const float* tr = xts + (size_t)cidx * D_;
#pragma unroll
    for (int c = 0; c < 8; ++c) {
      float4 a = *(const float4*)(xr + c * 4);
      float4 b = *(const float4*)(tr + c * 4);
      d = fmaf(a.x, b.x, d); d = fmaf(a.y, b.y, d);
      d = fmaf(a.z, b.z, d); d = fmaf(a.w, b.w, d);
    }
    sqex = fmaxf(xqn[q] + xtn[cidx] - 2.0f * d, 0.0f);
  }

  float s5[5]; int id5[5];
#pragma unroll
  for (int k = 0; k < 5; ++k) { s5[k] = 3.0e38f; id5[k] = 0; }
#pragma unroll
  for (int m = 0; m < NCAND; ++m) {
    float v  = __shfl(sqex, m);
    int   vi = __shfl(cidx, m);
    if (v < s5[4]) insert5f(s5, id5, v, vi);   // wave-uniform branch
  }

  float dinv[5]; float wsum = 0.f;
#pragma unroll
  for (int k = 0; k < 5; ++k) {
    dinv[k] = 1.0f / sqrtf(s5[k] + EPS_);
    wsum += dinv[k];
  }
  if (lane < OUT_) {
    float acc = 0.f;
#pragma unroll
    for (int k = 0; k < 5; ++k)
      acc = fmaf(dinv[k] / wsum, ty[(size_t)id5[k] * OUT_ + lane], acc);
    out[(size_t)q * OUT_ + lane] = acc;
  }
}

// ---------------------------------------------------------------------------
extern "C" void kernel_launch(void* const* d_in, const int* in_sizes, int n_in,
                              void* d_out, int out_size, void* d_ws, size_t ws_size,
                              hipStream_t stream) {
  const float* x   = (const float*)d_in[0];
  const float* tx  = (const float*)d_in[1];
  const float* ty  = (const float*)d_in[2];
  const float* wts = (const float*)d_in[3];
  float* out = (float*)d_out;

  char* ws = (char*)d_ws;
  size_t off = 0;
  float* xqs = (float*)(ws + off); off += (size_t)N_Q * D_ * 4;      // 512KB
  float* xts = (float*)(ws + off); off += (size_t)M_T * D_ * 4;      // 2MB
  float* xqn = (float*)(ws + off); off += (size_t)N_Q * 4;
  float* xtn = (float*)(ws + off); off += (size_t)M_T * 4;
  unsigned short* xq_h = (unsigned short*)(ws + off); off += (size_t)N_Q * D_ * 2;
  unsigned short* xq_l = (unsigned short*)(ws + off); off += (size_t)N_Q * D_ * 2;
  unsigned short* xt_h = (unsigned short*)(ws + off); off += (size_t)M_T * D_ * 2;
  unsigned short* xt_l = (unsigned short*)(ws + off); off += (size_t)M_T * D_ * 2;
  unsigned int* pkey = (unsigned int*)(ws + off);                    // 4096*80*4 = 1.3MB

  p0_prep<<<dim3((N_Q + M_T) * 4 / 256), dim3(256), 0, stream>>>(
      x, tx, wts, xqs, xts, xqn, xtn, xq_h, xq_l, xt_h, xt_l);
  p1_topk<<<dim3(NCHUNK, N_Q / 128), dim3(256), 0, stream>>>(
      xq_h, xq_l, xt_h, xt_l, xtn, pkey);
  p2_merge<<<dim3(N_Q * 64 / 256), dim3(256), 0, stream>>>(
      pkey, xqs, xqn, xts, xtn, ty, out);
}

// Round 10
// 123.352 us; speedup vs baseline: 1.3193x; 1.0908x over previous
//
#include <hip/hip_runtime.h>

#define N_Q 4096
#define M_T 16384
#define D_ 32
#define OUT_ 16
#define EPS_ 1e-6f
#define NCHUNK 16            // M-chunks (blockIdx.x)
#define CPTS (M_T / NCHUNK)  // 1024 points per chunk
#define TPTS 256             // points per LDS tile
#define NTILE (CPTS / TPTS)  // 4
#define NKEY 5               // per-lane keys (zero-loss for chunk top-5)
#define NCAND 12             // merged+rescored in phase 2
#define BIAS_ 128.0f
#define KMASK 0xFFFFC000u

typedef short bf16x8 __attribute__((ext_vector_type(8)));
typedef float f32x4 __attribute__((ext_vector_type(4)));

static __device__ __forceinline__ unsigned short f2bf(float f) {
  unsigned int u = __float_as_uint(f);
  return (unsigned short)((u + 0x7FFFu + ((u >> 16) & 1u)) >> 16);  // RNE
}
static __device__ __forceinline__ float bf2f(unsigned short h) {
  return __uint_as_float(((unsigned int)h) << 16);
}

__device__ __forceinline__ void chain5(unsigned int (&a)[NKEY], unsigned int v) {
#pragma unroll
  for (int i = 0; i < NKEY; ++i) {
    unsigned int lo = min(a[i], v);
    v = max(a[i], v);
    a[i] = lo;
  }
}
__device__ __forceinline__ void chain12(unsigned int (&a)[NCAND], unsigned int v) {
#pragma unroll
  for (int i = 0; i < NCAND; ++i) {
    unsigned int lo = min(a[i], v);
    v = max(a[i], v);
    a[i] = lo;
  }
}
__device__ __forceinline__ void insert5f(float (&s)[5], int (&id)[5], float v, int vi) {
  float cs = v; int ci = vi;
#pragma unroll
  for (int k = 0; k < 5; ++k) {
    bool lt = cs < s[k];
    float ts = s[k]; int ti = id[k];
    s[k] = lt ? cs : ts;  id[k] = lt ? ci : ti;
    cs   = lt ? ts : cs;  ci    = lt ? ti : ci;
  }
}

// ---------------------------------------------------------------------------
// Phase 0: scale by exp(w); fp32 copies + norms; bf16 hi/lo (queries) and
// bf16 hi (train) in tileT layout: row R, kgroup g at ushort offset
// (R>>4)*512 + g*128 + (R&15)*8.  Thread = (row, kgroup).
// ---------------------------------------------------------------------------
__global__ __launch_bounds__(256) void p0_prep(const float* __restrict__ x,
                                               const float* __restrict__ tx,
                                               const float* __restrict__ wts,
                                               float* __restrict__ xqs,
                                               float* __restrict__ xts,
                                               float* __restrict__ xqn,
                                               float* __restrict__ xtn,
                                               unsigned short* __restrict__ xq_h,
                                               unsigned short* __restrict__ xq_l,
                                               unsigned short* __restrict__ xt_h) {
  int gid = blockIdx.x * 256 + threadIdx.x;
  int row = gid >> 2;
  int g   = gid & 3;
  if (row >= N_Q + M_T) return;
  bool isq = row < N_Q;
  const float* src; float* dstf; unsigned short* dh; float* ndst; int ri;
  if (isq) { src = x;  dstf = xqs; dh = xq_h; ndst = xqn; ri = row; }
  else     { src = tx; dstf = xts; dh = xt_h; ndst = xtn; ri = row - N_Q; }
  float4 a = *(const float4*)(src + (size_t)ri * D_ + g * 8);
  float4 b = *(const float4*)(src + (size_t)ri * D_ + g * 8 + 4);
  float v[8] = {a.x, a.y, a.z, a.w, b.x, b.y, b.z, b.w};
  float nrm = 0.f;
  unsigned short hh[8], ll[8];
#pragma unroll
  for (int i = 0; i < 8; ++i) {
    float s = expf(wts[g * 8 + i]);
    v[i] /= s;
    nrm = fmaf(v[i], v[i], nrm);
    hh[i] = f2bf(v[i]);
    ll[i] = f2bf(v[i] - bf2f(hh[i]));
  }
  *(float4*)(dstf + (size_t)ri * D_ + g * 8)     = make_float4(v[0], v[1], v[2], v[3]);
  *(float4*)(dstf + (size_t)ri * D_ + g * 8 + 4) = make_float4(v[4], v[5], v[6], v[7]);
  nrm += __shfl_xor(nrm, 1);
  nrm += __shfl_xor(nrm, 2);
  if (g == 0) ndst[ri] = nrm;
  size_t ti = (size_t)(ri >> 4) * 512 + g * 128 + (ri & 15) * 8;  // ushort units
  uint4 hv;
  hv.x = hh[0] | (hh[1] << 16); hv.y = hh[2] | (hh[3] << 16);
  hv.z = hh[4] | (hh[5] << 16); hv.w = hh[6] | (hh[7] << 16);
  *(uint4*)(dh + ti) = hv;
  if (isq) {
    uint4 lv;
    lv.x = ll[0] | (ll[1] << 16); lv.y = ll[2] | (ll[3] << 16);
    lv.z = ll[4] | (ll[5] << 16); lv.w = ll[6] | (ll[7] << 16);
    *(uint4*)(xq_l + ti) = lv;
  }
}

// ---------------------------------------------------------------------------
// Phase 1: MFMA distance + branchless packed-key top-5.
// Block = 4 waves x 16 queries = 64 queries, one M-chunk of 1024 points.
// dot ~= (a_hi + a_lo) . b_hi  (2 MFMA; dropped a.b_lo term ~2^-9 rel, same
// order as key quantization; absorbed by exact top-12 rescore in p2).
// Per-thread state: 8 frag regs + 20 key regs -> no spill (r9: 40+16 spilled
// at the allocator's 64-reg occupancy target; WRITE_SIZE 177MB was scratch).
// C layout (r9-verified end-to-end): point col = lane&15, query row =
// (lane>>4)*4 + reg.
// ---------------------------------------------------------------------------
__global__ __launch_bounds__(256, 2) void p1_topk(const unsigned short* __restrict__ xq_h,
                                                  const unsigned short* __restrict__ xq_l,
                                                  const unsigned short* __restrict__ xt_h,
                                                  const float* __restrict__ xtn,
                                                  unsigned int* __restrict__ pkey) {
  __shared__ unsigned short sh[TPTS * D_];   // 16KB hi tile (tileT order)
  __shared__ float stn[TPTS];                // biased norms
  const int t = threadIdx.x;
  const int w = t >> 6, lane = t & 63;
  const int p = lane & 15, g = lane >> 4;
  const int chunk = blockIdx.x;
  const int qb = blockIdx.y * 64 + w * 16;

  // A-fragments: loop-invariant, 8 VGPRs
  const size_t abase = (size_t)(qb >> 4) * 512 + g * 128 + p * 8;
  const bf16x8 ah = *(const bf16x8*)(xq_h + abase);
  const bf16x8 al = *(const bf16x8*)(xq_l + abase);
  const f32x4 zero = {0.f, 0.f, 0.f, 0.f};

  unsigned int key[4][NKEY];
#pragma unroll
  for (int r = 0; r < 4; ++r)
#pragma unroll
    for (int k = 0; k < NKEY; ++k) key[r][k] = 0xFFFFFFFFu;

  for (int tt = 0; tt < NTILE; ++tt) {
    const int pbase = chunk * CPTS + tt * TPTS;
    // reg-staged tile loads issued early (hide under prior compute)
    uint4 vh[4];
    const size_t gb = (size_t)(pbase >> 4) * 512;
#pragma unroll
    for (int c = 0; c < 4; ++c)
      vh[c] = *(const uint4*)(xt_h + gb + (size_t)(w * 4 + c) * 512 + lane * 8);
    float tn1 = xtn[pbase + t] + BIAS_;
    __syncthreads();   // previous tile fully consumed
#pragma unroll
    for (int c = 0; c < 4; ++c)
      *(uint4*)(sh + (w * 4 + c) * 512 + lane * 8) = vh[c];
    stn[t] = tn1;
    __syncthreads();

#pragma unroll 4
    for (int s = 0; s < 16; ++s) {
      const bf16x8 bh = *(const bf16x8*)(sh + s * 512 + lane * 8);
      const float tnB = stn[s * 16 + p];
      f32x4 acc = __builtin_amdgcn_mfma_f32_16x16x32_bf16(al, bh, zero, 0, 0, 0);
      acc = __builtin_amdgcn_mfma_f32_16x16x32_bf16(ah, bh, acc, 0, 0, 0);
      const unsigned int kor = (unsigned int)(pbase + s * 16 + p);
#pragma unroll
      for (int r = 0; r < 4; ++r) {
        float v = fmaf(-2.0f, acc[r], tnB);            // > 0 by bias
        chain5(key[r], (__float_as_uint(v) & KMASK) | kor);
      }
    }
  }

  // merge across the 16 lanes (same g-group) holding each query's columns
#pragma unroll
  for (int r = 0; r < 4; ++r) {
#pragma unroll
    for (int step = 1; step < 16; step <<= 1) {
      unsigned int ov[NKEY];
#pragma unroll
      for (int k = 0; k < NKEY; ++k)
        ov[k] = (unsigned int)__shfl_xor((int)key[r][k], step);
#pragma unroll
      for (int k = 0; k < NKEY; ++k) chain5(key[r], ov[k]);
    }
    if (p < 5) {
      unsigned int val = key[r][0];
      val = (p == 1) ? key[r][1] : val;
      val = (p == 2) ? key[r][2] : val;
      val = (p == 3) ? key[r][3] : val;
      val = (p == 4) ? key[r][4] : val;
      // chunk-major: each block writes a contiguous 1280B region
      pkey[((size_t)chunk * N_Q + (qb + g * 4 + r)) * 5 + p] = val;
    }
  }
}

// ---------------------------------------------------------------------------
// Phase 2: one wave per query. 80 keys (16 chunks x 5) -> branchless top-12
// via chain + shfl_xor butterfly, exact fp32 rescore of 12, exact top-5.
// ---------------------------------------------------------------------------
__global__ __launch_bounds__(256) void p2_merge(const unsigned int* __restrict__ pkey,
                                                const float* __restrict__ xqs,
                                                const float* __restrict__ xqn,
                                                const float* __restrict__ xts,
                                                const float* __restrict__ xtn,
                                                const float* __restrict__ ty,
                                                float* __restrict__ out) {
  const int q    = (blockIdx.x * blockDim.x + threadIdx.x) >> 6;
  const int lane = threadIdx.x & 63;
  if (q >= N_Q) return;

  unsigned int s[NCAND];
#pragma unroll
  for (int m = 0; m < NCAND; ++m) s[m] = 0xFFFFFFFFu;
  {
    int c = lane;                      // keys 0..63
    int ch = c / 5, k = c - ch * 5;
    chain12(s, pkey[((size_t)ch * N_Q + q) * 5 + k]);
  }
  {
    unsigned int v = 0xFFFFFFFFu;      // keys 64..79
    if (lane < 16) {
      int c = 64 + lane;
      int ch = c / 5, k = c - ch * 5;
      v = pkey[((size_t)ch * N_Q + q) * 5 + k];
    }
    chain12(s, v);
  }

#pragma unroll
  for (int step = 1; step < 64; step <<= 1) {
    unsigned int ov[NCAND];
#pragma unroll
    for (int m = 0; m < NCAND; ++m) ov[m] = (unsigned int)__shfl_xor((int)s[m], step);
#pragma unroll
    for (int m = 0; m < NCAND; ++m) chain12(s, ov[m]);
  }

  unsigned int mykey = s[0];
#pragma unroll
  for (int m = 1; m < NCAND; ++m) mykey = (lane == m) ? s[m] : mykey;

  int   cidx = (int)(mykey & 0x3FFFu);
  float sqex = 3.0e38f;
  if (lane < NCAND) {
    float d = 0.f;
    const float* xr = xqs + (size_t)q * D_;
    const float* tr = xts + (size_t)cidx * D_;
#pragma unroll
    for (int c = 0; c < 8; ++c) {
      float4 a = *(const float4*)(xr + c * 4);
      float4 b = *(const float4*)(tr + c * 4);
      d = fmaf(a.x, b.x, d); d = fmaf(a.y, b.y, d);
      d = fmaf(a.z, b.z, d); d = fmaf(a.w, b.w, d);
    }
    sqex = fmaxf(xqn[q] + xtn[cidx] - 2.0f * d, 0.0f);
  }

  float s5[5]; int id5[5];
#pragma unroll
  for (int k = 0; k < 5; ++k) { s5[k] = 3.0e38f; id5[k] = 0; }
#pragma unroll
  for (int m = 0; m < NCAND; ++m) {
    float v  = __shfl(sqex, m);
    int   vi = __shfl(cidx, m);
    if (v < s5[4]) insert5f(s5, id5, v, vi);   // wave-uniform branch
  }

  float dinv[5]; float wsum = 0.f;
#pragma unroll
  for (int k = 0; k < 5; ++k) {
    dinv[k] = 1.0f / sqrtf(s5[k] + EPS_);
    wsum += dinv[k];
  }
  if (lane < OUT_) {
    float acc = 0.f;
#pragma unroll
    for (int k = 0; k < 5; ++k)
      acc = fmaf(dinv[k] / wsum, ty[(size_t)id5[k] * OUT_ + lane], acc);
    out[(size_t)q * OUT_ + lane] = acc;
  }
}

// ---------------------------------------------------------------------------
extern "C" void kernel_launch(void* const* d_in, const int* in_sizes, int n_in,
                              void* d_out, int out_size, void* d_ws, size_t ws_size,
                              hipStream_t stream) {
  const float* x   = (const float*)d_in[0];
  const float* tx  = (const float*)d_in[1];
  const float* ty  = (const float*)d_in[2];
  const float* wts = (const float*)d_in[3];
  float* out = (float*)d_out;

  char* ws = (char*)d_ws;
  size_t off = 0;
  float* xqs = (float*)(ws + off); off += (size_t)N_Q * D_ * 4;      // 512KB
  float* xts = (float*)(ws + off); off += (size_t)M_T * D_ * 4;      // 2MB
  float* xqn = (float*)(ws + off); off += (size_t)N_Q * 4;
  float* xtn = (float*)(ws + off); off += (size_t)M_T * 4;
  unsigned short* xq_h = (unsigned short*)(ws + off); off += (size_t)N_Q * D_ * 2;
  unsigned short* xq_l = (unsigned short*)(ws + off); off += (size_t)N_Q * D_ * 2;
  unsigned short* xt_h = (unsigned short*)(ws + off); off += (size_t)M_T * D_ * 2;
  unsigned int* pkey = (unsigned int*)(ws + off);                    // 1.3MB

  p0_prep<<<dim3((N_Q + M_T) * 4 / 256), dim3(256), 0, stream>>>(
      x, tx, wts, xqs, xts, xqn, xtn, xq_h, xq_l, xt_h);
  p1_topk<<<dim3(NCHUNK, N_Q / 64), dim3(256), 0, stream>>>(
      xq_h, xq_l, xt_h, xtn, pkey);
  p2_merge<<<dim3(N_Q * 64 / 256), dim3(256), 0, stream>>>(
      pkey, xqs, xqn, xts, xtn, ty, out);
}

// Round 12
// 113.705 us; speedup vs baseline: 1.4312x; 1.0848x over previous
//
#include <hip/hip_runtime.h>

#define N_Q 4096
#define M_T 16384
#define D_ 32
#define OUT_ 16
#define EPS_ 1e-6f
#define NCHUNK 16            // M-chunks (blockIdx.x)
#define CPTS (M_T / NCHUNK)  // 1024 points per chunk
#define TPTS 256             // points per LDS tile
#define NTILE (CPTS / TPTS)  // 4
#define NKEY 5               // per-lane keys (zero-loss for chunk top-5)
#define NCAND 12             // merged+rescored in phase 2
#define BIAS_ 128.0f
#define KMASK 0xFFFFC000u

typedef short bf16x8 __attribute__((ext_vector_type(8)));
typedef float f32x4 __attribute__((ext_vector_type(4)));

static __device__ __forceinline__ unsigned short f2bf(float f) {
  unsigned int u = __float_as_uint(f);
  return (unsigned short)((u + 0x7FFFu + ((u >> 16) & 1u)) >> 16);  // RNE
}
static __device__ __forceinline__ float bf2f(unsigned short h) {
  return __uint_as_float(((unsigned int)h) << 16);
}

__device__ __forceinline__ void chain5(unsigned int (&a)[NKEY], unsigned int v) {
#pragma unroll
  for (int i = 0; i < NKEY; ++i) {
    unsigned int lo = min(a[i], v);
    v = max(a[i], v);
    a[i] = lo;
  }
}
__device__ __forceinline__ void chain12(unsigned int (&a)[NCAND], unsigned int v) {
#pragma unroll
  for (int i = 0; i < NCAND; ++i) {
    unsigned int lo = min(a[i], v);
    v = max(a[i], v);
    a[i] = lo;
  }
}
__device__ __forceinline__ void insert5f(float (&s)[5], int (&id)[5], float v, int vi) {
  float cs = v; int ci = vi;
#pragma unroll
  for (int k = 0; k < 5; ++k) {
    bool lt = cs < s[k];
    float ts = s[k]; int ti = id[k];
    s[k] = lt ? cs : ts;  id[k] = lt ? ci : ti;
    cs   = lt ? ts : cs;  ci    = lt ? ti : ci;
  }
}

// ---------------------------------------------------------------------------
// Phase 0: scale by exp(w); fp32 copies + norms; bf16 hi/lo (queries) and
// bf16 hi (train) in tileT layout: row R, kgroup g at ushort offset
// (R>>4)*512 + g*128 + (R&15)*8.  Thread = (row, kgroup).
// ---------------------------------------------------------------------------
__global__ __launch_bounds__(256) void p0_prep(const float* __restrict__ x,
                                               const float* __restrict__ tx,
                                               const float* __restrict__ wts,
                                               float* __restrict__ xqs,
                                               float* __restrict__ xts,
                                               float* __restrict__ xqn,
                                               float* __restrict__ xtn,
                                               unsigned short* __restrict__ xq_h,
                                               unsigned short* __restrict__ xq_l,
                                               unsigned short* __restrict__ xt_h) {
  int gid = blockIdx.x * 256 + threadIdx.x;
  int row = gid >> 2;
  int g   = gid & 3;
  if (row >= N_Q + M_T) return;
  bool isq = row < N_Q;
  const float* src; float* dstf; unsigned short* dh; float* ndst; int ri;
  if (isq) { src = x;  dstf = xqs; dh = xq_h; ndst = xqn; ri = row; }
  else     { src = tx; dstf = xts; dh = xt_h; ndst = xtn; ri = row - N_Q; }
  float4 a = *(const float4*)(src + (size_t)ri * D_ + g * 8);
  float4 b = *(const float4*)(src + (size_t)ri * D_ + g * 8 + 4);
  float v[8] = {a.x, a.y, a.z, a.w, b.x, b.y, b.z, b.w};
  float nrm = 0.f;
  unsigned short hh[8], ll[8];
#pragma unroll
  for (int i = 0; i < 8; ++i) {
    float s = expf(wts[g * 8 + i]);
    v[i] /= s;
    nrm = fmaf(v[i], v[i], nrm);
    hh[i] = f2bf(v[i]);
    ll[i] = f2bf(v[i] - bf2f(hh[i]));
  }
  *(float4*)(dstf + (size_t)ri * D_ + g * 8)     = make_float4(v[0], v[1], v[2], v[3]);
  *(float4*)(dstf + (size_t)ri * D_ + g * 8 + 4) = make_float4(v[4], v[5], v[6], v[7]);
  nrm += __shfl_xor(nrm, 1);
  nrm += __shfl_xor(nrm, 2);
  if (g == 0) ndst[ri] = nrm;
  size_t ti = (size_t)(ri >> 4) * 512 + g * 128 + (ri & 15) * 8;  // ushort units
  uint4 hv;
  hv.x = hh[0] | (hh[1] << 16); hv.y = hh[2] | (hh[3] << 16);
  hv.z = hh[4] | (hh[5] << 16); hv.w = hh[6] | (hh[7] << 16);
  *(uint4*)(dh + ti) = hv;
  if (isq) {
    uint4 lv;
    lv.x = ll[0] | (ll[1] << 16); lv.y = ll[2] | (ll[3] << 16);
    lv.z = ll[4] | (ll[5] << 16); lv.w = ll[6] | (ll[7] << 16);
    *(uint4*)(xq_l + ti) = lv;
  }
}

// ---------------------------------------------------------------------------
// Phase 1: MFMA distance + branchless packed-key top-5.
// Block = 4 waves x 16 queries = 64 queries, one M-chunk of 1024 points.
// dot ~= (a_hi + a_lo) . b_hi  (2 MFMA; error absorbed by exact top-12
// rescore in p2 — machinery verified r5/r9/r10).
// Tile staging via global_load_lds (wave-uniform LDS base + lane*16B, which
// the tileT layout matches exactly): removes the 8xuint4 reg staging whose
// barrier-straddling live ranges the allocator kept spilling (r9: 177MB,
// r10: 155MB scratch write-back at VGPR=64/36).
// C layout (r9/r10-verified end-to-end): point col = lane&15,
// query row = (lane>>4)*4 + reg.
// ---------------------------------------------------------------------------
__global__ __launch_bounds__(256, 1) void p1_topk(const unsigned short* __restrict__ xq_h,
                                                  const unsigned short* __restrict__ xq_l,
                                                  const unsigned short* __restrict__ xt_h,
                                                  const float* __restrict__ xtn,
                                                  unsigned int* __restrict__ pkey) {
  __shared__ __align__(16) unsigned short sh[TPTS * D_];  // 16KB hi tile (tileT order)
  __shared__ float stn[TPTS];                             // biased norms
  const int t = threadIdx.x;
  const int w = t >> 6, lane = t & 63;
  const int p = lane & 15, g = lane >> 4;
  const int chunk = blockIdx.x;
  const int qb = blockIdx.y * 64 + w * 16;

  // A-fragments: loop-invariant, 8 VGPRs
  const size_t abase = (size_t)(qb >> 4) * 512 + g * 128 + p * 8;
  const bf16x8 ah = *(const bf16x8*)(xq_h + abase);
  const bf16x8 al = *(const bf16x8*)(xq_l + abase);
  const f32x4 zero = {0.f, 0.f, 0.f, 0.f};

  unsigned int key[4][NKEY];
#pragma unroll
  for (int r = 0; r < 4; ++r)
#pragma unroll
    for (int k = 0; k < NKEY; ++k) key[r][k] = 0xFFFFFFFFu;

  for (int tt = 0; tt < NTILE; ++tt) {
    const int pbase = chunk * CPTS + tt * TPTS;
    const size_t gb = (size_t)(pbase >> 4) * 512;
    __syncthreads();   // previous tile fully consumed
#pragma unroll
    for (int c = 0; c < 4; ++c) {
      // global src is per-lane (+lane*16B); LDS dst is wave-uniform base,
      // HW scatters lane i to base + i*16.
      __builtin_amdgcn_global_load_lds(
          (const __attribute__((address_space(1))) void*)(xt_h + gb + (size_t)(w * 4 + c) * 512 + (size_t)lane * 8),
          (__attribute__((address_space(3))) void*)(sh + (w * 4 + c) * 512),
          16, 0, 0);
    }
    stn[t] = xtn[pbase + t] + BIAS_;
    __syncthreads();   // drains vmcnt + lgkm: tile ready

#pragma unroll 2
    for (int s = 0; s < 16; ++s) {
      const bf16x8 bh = *(const bf16x8*)(sh + s * 512 + lane * 8);
      const float tnB = stn[s * 16 + p];
      f32x4 acc = __builtin_amdgcn_mfma_f32_16x16x32_bf16(al, bh, zero, 0, 0, 0);
      acc = __builtin_amdgcn_mfma_f32_16x16x32_bf16(ah, bh, acc, 0, 0, 0);
      const unsigned int kor = (unsigned int)(pbase + s * 16 + p);
#pragma unroll
      for (int r = 0; r < 4; ++r) {
        float v = fmaf(-2.0f, acc[r], tnB);            // > 0 by bias
        chain5(key[r], (__float_as_uint(v) & KMASK) | kor);
      }
    }
  }

  // merge across the 16 lanes (same g-group) holding each query's columns
#pragma unroll
  for (int r = 0; r < 4; ++r) {
#pragma unroll
    for (int step = 1; step < 16; step <<= 1) {
      unsigned int ov[NKEY];
#pragma unroll
      for (int k = 0; k < NKEY; ++k)
        ov[k] = (unsigned int)__shfl_xor((int)key[r][k], step);
#pragma unroll
      for (int k = 0; k < NKEY; ++k) chain5(key[r], ov[k]);
    }
    if (p < 5) {
      unsigned int val = key[r][0];
      val = (p == 1) ? key[r][1] : val;
      val = (p == 2) ? key[r][2] : val;
      val = (p == 3) ? key[r][3] : val;
      val = (p == 4) ? key[r][4] : val;
      // chunk-major: each block writes a contiguous 1280B region
      pkey[((size_t)chunk * N_Q + (qb + g * 4 + r)) * 5 + p] = val;
    }
  }
}

// ---------------------------------------------------------------------------
// Phase 2: one wave per query. 80 keys (16 chunks x 5) -> branchless top-12
// via chain + shfl_xor butterfly, exact fp32 rescore of 12, exact top-5.
// ---------------------------------------------------------------------------
__global__ __launch_bounds__(256) void p2_merge(const unsigned int* __restrict__ pkey,
                                                const float* __restrict__ xqs,
                                                const float* __restrict__ xqn,
                                                const float* __restrict__ xts,
                                                const float* __restrict__ xtn,
                                                const float* __restrict__ ty,
                                                float* __restrict__ out) {
  const int q    = (blockIdx.x * blockDim.x + threadIdx.x) >> 6;
  const int lane = threadIdx.x & 63;
  if (q >= N_Q) return;

  unsigned int s[NCAND];
#pragma unroll
  for (int m = 0; m < NCAND; ++m) s[m] = 0xFFFFFFFFu;
  {
    int c = lane;                      // keys 0..63
    int ch = c / 5, k = c - ch * 5;
    chain12(s, pkey[((size_t)ch * N_Q + q) * 5 + k]);
  }
  {
    unsigned int v = 0xFFFFFFFFu;      // keys 64..79
    if (lane < 16) {
      int c = 64 + lane;
      int ch = c / 5, k = c - ch * 5;
      v = pkey[((size_t)ch * N_Q + q) * 5 + k];
    }
    chain12(s, v);
  }

#pragma unroll
  for (int step = 1; step < 64; step <<= 1) {
    unsigned int ov[NCAND];
#pragma unroll
    for (int m = 0; m < NCAND; ++m) ov[m] = (unsigned int)__shfl_xor((int)s[m], step);
#pragma unroll
    for (int m = 0; m < NCAND; ++m) chain12(s, ov[m]);
  }

  unsigned int mykey = s[0];
#pragma unroll
  for (int m = 1; m < NCAND; ++m) mykey = (lane == m) ? s[m] : mykey;

  int   cidx = (int)(mykey & 0x3FFFu);
  float sqex = 3.0e38f;
  if (lane < NCAND) {
    float d = 0.f;
    const float* xr = xqs + (size_t)q * D_;
    const float* tr = xts + (size_t)cidx * D_;
#pragma unroll
    for (int c = 0; c < 8; ++c) {
      float4 a = *(const float4*)(xr + c * 4);
      float4 b = *(const float4*)(tr + c * 4);
      d = fmaf(a.x, b.x, d); d = fmaf(a.y, b.y, d);
      d = fmaf(a.z, b.z, d); d = fmaf(a.w, b.w, d);
    }
    sqex = fmaxf(xqn[q] + xtn[cidx] - 2.0f * d, 0.0f);
  }

  float s5[5]; int id5[5];
#pragma unroll
  for (int k = 0; k < 5; ++k) { s5[k] = 3.0e38f; id5[k] = 0; }
#pragma unroll
  for (int m = 0; m < NCAND; ++m) {
    float v  = __shfl(sqex, m);
    int   vi = __shfl(cidx, m);
    if (v < s5[4]) insert5f(s5, id5, v, vi);   // wave-uniform branch
  }

  float dinv[5]; float wsum = 0.f;
#pragma unroll
  for (int k = 0; k < 5; ++k) {
    dinv[k] = 1.0f / sqrtf(s5[k] + EPS_);
    wsum += dinv[k];
  }
  if (lane < OUT_) {
    float acc = 0.f;
#pragma unroll
    for (int k = 0; k < 5; ++k)
      acc = fmaf(dinv[k] / wsum, ty[(size_t)id5[k] * OUT_ + lane], acc);
    out[(size_t)q * OUT_ + lane] = acc;
  }
}

// ---------------------------------------------------------------------------
extern "C" void kernel_launch(void* const* d_in, const int* in_sizes, int n_in,
                              void* d_out, int out_size, void* d_ws, size_t ws_size,
                              hipStream_t stream) {
  const float* x   = (const float*)d_in[0];
  const float* tx  = (const float*)d_in[1];
  const float* ty  = (const float*)d_in[2];
  const float* wts = (const float*)d_in[3];
  float* out = (float*)d_out;

  char* ws = (char*)d_ws;
  size_t off = 0;
  float* xqs = (float*)(ws + off); off += (size_t)N_Q * D_ * 4;      // 512KB
  float* xts = (float*)(ws + off); off += (size_t)M_T * D_ * 4;      // 2MB
  float* xqn = (float*)(ws + off); off += (size_t)N_Q * 4;
  float* xtn = (float*)(ws + off); off += (size_t)M_T * 4;
  unsigned short* xq_h = (unsigned short*)(ws + off); off += (size_t)N_Q * D_ * 2;
  unsigned short* xq_l = (unsigned short*)(ws + off); off += (size_t)N_Q * D_ * 2;
  unsigned short* xt_h = (unsigned short*)(ws + off); off += (size_t)M_T * D_ * 2;
  unsigned int* pkey = (unsigned int*)(ws + off);                    // 1.3MB

  p0_prep<<<dim3((N_Q + M_T) * 4 / 256), dim3(256), 0, stream>>>(
      x, tx, wts, xqs, xts, xqn, xtn, xq_h, xq_l, xt_h);
  p1_topk<<<dim3(NCHUNK, N_Q / 64), dim3(256), 0, stream>>>(
      xq_h, xq_l, xt_h, xtn, pkey);
  p2_merge<<<dim3(N_Q * 64 / 256), dim3(256), 0, stream>>>(
      pkey, xqs, xqn, xts, xtn, ty, out);
}

// Round 13
// 107.136 us; speedup vs baseline: 1.5189x; 1.0613x over previous
//
#include <hip/hip_runtime.h>

#define N_Q 4096
#define M_T 16384
#define D_ 32
#define OUT_ 16
#define EPS_ 1e-6f
#define NCHUNK 32            // M-chunks (blockIdx.x)
#define CPTS (M_T / NCHUNK)  // 512 points per chunk
#define TPTS 256             // points per LDS tile
#define NTILE (CPTS / TPTS)  // 2
#define NKEY 5               // per-lane keys (zero-loss for chunk top-5)
#define NCAND 12             // merged+rescored in phase 2
#define BIAS_ 128.0f
#define KMASK 0xFFFFC000u

typedef short bf16x8 __attribute__((ext_vector_type(8)));
typedef float f32x4 __attribute__((ext_vector_type(4)));

static __device__ __forceinline__ unsigned short f2bf(float f) {
  unsigned int u = __float_as_uint(f);
  return (unsigned short)((u + 0x7FFFu + ((u >> 16) & 1u)) >> 16);  // RNE
}
static __device__ __forceinline__ float bf2f(unsigned short h) {
  return __uint_as_float(((unsigned int)h) << 16);
}

__device__ __forceinline__ void chain5(unsigned int (&a)[NKEY], unsigned int v) {
#pragma unroll
  for (int i = 0; i < NKEY; ++i) {
    unsigned int lo = min(a[i], v);
    v = max(a[i], v);
    a[i] = lo;
  }
}
__device__ __forceinline__ void chain12(unsigned int (&a)[NCAND], unsigned int v) {
#pragma unroll
  for (int i = 0; i < NCAND; ++i) {
    unsigned int lo = min(a[i], v);
    v = max(a[i], v);
    a[i] = lo;
  }
}
__device__ __forceinline__ void insert5f(float (&s)[5], int (&id)[5], float v, int vi) {
  float cs = v; int ci = vi;
#pragma unroll
  for (int k = 0; k < 5; ++k) {
    bool lt = cs < s[k];
    float ts = s[k]; int ti = id[k];
    s[k] = lt ? cs : ts;  id[k] = lt ? ci : ti;
    cs   = lt ? ts : cs;  ci    = lt ? ti : ci;
  }
}

// ---------------------------------------------------------------------------
// Phase 0: scale by exp(w); fp32 copies + norms; bf16 hi/lo (queries) and
// bf16 hi (train) in tileT layout: row R, kgroup g at ushort offset
// (R>>4)*512 + g*128 + (R&15)*8.  Thread = (row, kgroup).
// ---------------------------------------------------------------------------
__global__ __launch_bounds__(256) void p0_prep(const float* __restrict__ x,
                                               const float* __restrict__ tx,
                                               const float* __restrict__ wts,
                                               float* __restrict__ xqs,
                                               float* __restrict__ xts,
                                               float* __restrict__ xqn,
                                               float* __restrict__ xtn,
                                               unsigned short* __restrict__ xq_h,
                                               unsigned short* __restrict__ xq_l,
                                               unsigned short* __restrict__ xt_h) {
  int gid = blockIdx.x * 256 + threadIdx.x;
  int row = gid >> 2;
  int g   = gid & 3;
  if (row >= N_Q + M_T) return;
  bool isq = row < N_Q;
  const float* src; float* dstf; unsigned short* dh; float* ndst; int ri;
  if (isq) { src = x;  dstf = xqs; dh = xq_h; ndst = xqn; ri = row; }
  else     { src = tx; dstf = xts; dh = xt_h; ndst = xtn; ri = row - N_Q; }
  float4 a = *(const float4*)(src + (size_t)ri * D_ + g * 8);
  float4 b = *(const float4*)(src + (size_t)ri * D_ + g * 8 + 4);
  float v[8] = {a.x, a.y, a.z, a.w, b.x, b.y, b.z, b.w};
  float nrm = 0.f;
  unsigned short hh[8], ll[8];
#pragma unroll
  for (int i = 0; i < 8; ++i) {
    float s = expf(wts[g * 8 + i]);
    v[i] /= s;
    nrm = fmaf(v[i], v[i], nrm);
    hh[i] = f2bf(v[i]);
    ll[i] = f2bf(v[i] - bf2f(hh[i]));
  }
  *(float4*)(dstf + (size_t)ri * D_ + g * 8)     = make_float4(v[0], v[1], v[2], v[3]);
  *(float4*)(dstf + (size_t)ri * D_ + g * 8 + 4) = make_float4(v[4], v[5], v[6], v[7]);
  nrm += __shfl_xor(nrm, 1);
  nrm += __shfl_xor(nrm, 2);
  if (g == 0) ndst[ri] = nrm;
  size_t ti = (size_t)(ri >> 4) * 512 + g * 128 + (ri & 15) * 8;  // ushort units
  uint4 hv;
  hv.x = hh[0] | (hh[1] << 16); hv.y = hh[2] | (hh[3] << 16);
  hv.z = hh[4] | (hh[5] << 16); hv.w = hh[6] | (hh[7] << 16);
  *(uint4*)(dh + ti) = hv;
  if (isq) {
    uint4 lv;
    lv.x = ll[0] | (ll[1] << 16); lv.y = ll[2] | (ll[3] << 16);
    lv.z = ll[4] | (ll[5] << 16); lv.w = ll[6] | (ll[7] << 16);
    *(uint4*)(xq_l + ti) = lv;
  }
}

// ---------------------------------------------------------------------------
// Phase 1: MFMA distance + branchless packed-key top-5.
// Block = 4 waves x 16 queries = 64 queries, one M-chunk of 512 points.
// dot ~= (a_hi + a_lo) . b_hi; error absorbed by exact top-12 rescore (p2).
// Staging via global_load_lds (r12: WRITE 155->49MB). This round: the
// 16-lane shfl_xor butterfly (keys+ov all live -> the remaining 49MB spill)
// is replaced by a two-stage LDS merge in a union-overlaid buffer.
// C layout (r9..r12-verified): point col = lane&15, query row = (lane>>4)*4+reg.
// ---------------------------------------------------------------------------
union P1Smem {
  struct { unsigned short sh[TPTS * D_]; float stn[TPTS]; } loop;   // 16KB + 1KB
  struct { unsigned int kbuf[64 * 16 * NKEY]; unsigned int s1[64 * 4 * NKEY]; } mrg; // 20KB + 5KB
};

__global__ __launch_bounds__(256, 1) void p1_topk(const unsigned short* __restrict__ xq_h,
                                                  const unsigned short* __restrict__ xq_l,
                                                  const unsigned short* __restrict__ xt_h,
                                                  const float* __restrict__ xtn,
                                                  unsigned int* __restrict__ pkey) {
  __shared__ __align__(16) P1Smem sm;
  const int t = threadIdx.x;
  const int w = t >> 6, lane = t & 63;
  const int p = lane & 15, g = lane >> 4;
  const int chunk = blockIdx.x;
  const int qbB = blockIdx.y * 64;        // block query base
  const int qb  = qbB + w * 16;           // wave query base

  // A-fragments: loop-invariant, 8 VGPRs
  const size_t abase = (size_t)(qb >> 4) * 512 + g * 128 + p * 8;
  const bf16x8 ah = *(const bf16x8*)(xq_h + abase);
  const bf16x8 al = *(const bf16x8*)(xq_l + abase);
  const f32x4 zero = {0.f, 0.f, 0.f, 0.f};

  unsigned int key[4][NKEY];
#pragma unroll
  for (int r = 0; r < 4; ++r)
#pragma unroll
    for (int k = 0; k < NKEY; ++k) key[r][k] = 0xFFFFFFFFu;

  for (int tt = 0; tt < NTILE; ++tt) {
    const int pbase = chunk * CPTS + tt * TPTS;
    const size_t gb = (size_t)(pbase >> 4) * 512;
    __syncthreads();   // previous tile fully consumed
#pragma unroll
    for (int c = 0; c < 4; ++c) {
      __builtin_amdgcn_global_load_lds(
          (const __attribute__((address_space(1))) void*)(xt_h + gb + (size_t)(w * 4 + c) * 512 + (size_t)lane * 8),
          (__attribute__((address_space(3))) void*)(sm.loop.sh + (w * 4 + c) * 512),
          16, 0, 0);
    }
    sm.loop.stn[t] = xtn[pbase + t] + BIAS_;
    __syncthreads();   // drains vmcnt + lgkm: tile ready

#pragma unroll 2
    for (int s = 0; s < 16; ++s) {
      const bf16x8 bh = *(const bf16x8*)(sm.loop.sh + s * 512 + lane * 8);
      const float tnB = sm.loop.stn[s * 16 + p];
      f32x4 acc = __builtin_amdgcn_mfma_f32_16x16x32_bf16(al, bh, zero, 0, 0, 0);
      acc = __builtin_amdgcn_mfma_f32_16x16x32_bf16(ah, bh, acc, 0, 0, 0);
      const unsigned int kor = (unsigned int)(pbase + s * 16 + p);
#pragma unroll
      for (int r = 0; r < 4; ++r) {
        float v = fmaf(-2.0f, acc[r], tnB);            // > 0 by bias
        chain5(key[r], (__float_as_uint(v) & KMASK) | kor);
      }
    }
  }

  // ---- two-stage LDS merge (replaces shuffle butterfly; no high-pressure
  //      live ranges -> nothing to spill) ----
  __syncthreads();   // all waves done reading the tile buffer
#pragma unroll
  for (int r = 0; r < 4; ++r) {
    const int ql = w * 16 + g * 4 + r;     // local query id 0..63
#pragma unroll
    for (int k = 0; k < NKEY; ++k)
      sm.mrg.kbuf[(ql * 16 + p) * NKEY + k] = key[r][k];
  }
  __syncthreads();

  {  // stage 1: 256 threads, each merges 4 lanes (20 contiguous dwords)
    const int ql = t & 63, quarter = t >> 6;
    unsigned int m1[NKEY];
#pragma unroll
    for (int k = 0; k < NKEY; ++k) m1[k] = 0xFFFFFFFFu;
    const unsigned int* src = sm.mrg.kbuf + (ql * 16 + quarter * 4) * NKEY;
#pragma unroll
    for (int i = 0; i < 4 * NKEY; ++i) chain5(m1, src[i]);
    __syncthreads();   // kbuf fully read before s1 overwrites nothing (disjoint) — order only
#pragma unroll
    for (int k = 0; k < NKEY; ++k)
      sm.mrg.s1[(ql * 4 + quarter) * NKEY + k] = m1[k];
  }
  __syncthreads();

  if (t < 64) {  // stage 2: one thread per query -> final 5 keys, coalesced out
    unsigned int m2[NKEY];
#pragma unroll
    for (int k = 0; k < NKEY; ++k) m2[k] = 0xFFFFFFFFu;
    const unsigned int* src = sm.mrg.s1 + t * 4 * NKEY;
#pragma unroll
    for (int i = 0; i < 4 * NKEY; ++i) chain5(m2, src[i]);
#pragma unroll
    for (int k = 0; k < NKEY; ++k)
      pkey[((size_t)chunk * N_Q + (qbB + t)) * NKEY + k] = m2[k];
  }
}

// ---------------------------------------------------------------------------
// Phase 2: one wave per query. 160 keys (32 chunks x 5) -> branchless top-12
// via chain + shfl_xor butterfly, exact fp32 rescore of 12, exact top-5.
// ---------------------------------------------------------------------------
__global__ __launch_bounds__(256) void p2_merge(const unsigned int* __restrict__ pkey,
                                                const float* __restrict__ xqs,
                                                const float* __restrict__ xqn,
                                                const float* __restrict__ xts,
                                                const float* __restrict__ xtn,
                                                const float* __restrict__ ty,
                                                float* __restrict__ out) {
  const int q    = (blockIdx.x * blockDim.x + threadIdx.x) >> 6;
  const int lane = threadIdx.x & 63;
  if (q >= N_Q) return;

  unsigned int s[NCAND];
#pragma unroll
  for (int m = 0; m < NCAND; ++m) s[m] = 0xFFFFFFFFu;
  {
    int c = lane;                      // keys 0..63
    int ch = c / 5, k = c - ch * 5;
    chain12(s, pkey[((size_t)ch * N_Q + q) * 5 + k]);
  }
  {
    int c = lane + 64;                 // keys 64..127
    int ch = c / 5, k = c - ch * 5;
    chain12(s, pkey[((size_t)ch * N_Q + q) * 5 + k]);
  }
  {
    unsigned int v = 0xFFFFFFFFu;      // keys 128..159
    if (lane < 32) {
      int c = 128 + lane;
      int ch = c / 5, k = c - ch * 5;
      v = pkey[((size_t)ch * N_Q + q) * 5 + k];
    }
    chain12(s, v);
  }

#pragma unroll
  for (int step = 1; step < 64; step <<= 1) {
    unsigned int ov[NCAND];
#pragma unroll
    for (int m = 0; m < NCAND; ++m) ov[m] = (unsigned int)__shfl_xor((int)s[m], step);
#pragma unroll
    for (int m = 0; m < NCAND; ++m) chain12(s, ov[m]);
  }

  unsigned int mykey = s[0];
#pragma unroll
  for (int m = 1; m < NCAND; ++m) mykey = (lane == m) ? s[m] : mykey;

  int   cidx = (int)(mykey & 0x3FFFu);
  float sqex = 3.0e38f;
  if (lane < NCAND) {
    float d = 0.f;
    const float* xr = xqs + (size_t)q * D_;
    const float* tr = xts + (size_t)cidx * D_;
#pragma unroll
    for (int c = 0; c < 8; ++c) {
      float4 a = *(const float4*)(xr + c * 4);
      float4 b = *(const float4*)(tr + c * 4);
      d = fmaf(a.x, b.x, d); d = fmaf(a.y, b.y, d);
      d = fmaf(a.z, b.z, d); d = fmaf(a.w, b.w, d);
    }
    sqex = fmaxf(xqn[q] + xtn[cidx] - 2.0f * d, 0.0f);
  }

  float s5[5]; int id5[5];
#pragma unroll
  for (int k = 0; k < 5; ++k) { s5[k] = 3.0e38f; id5[k] = 0; }
#pragma unroll
  for (int m = 0; m < NCAND; ++m) {
    float v  = __shfl(sqex, m);
    int   vi = __shfl(cidx, m);
    if (v < s5[4]) insert5f(s5, id5, v, vi);   // wave-uniform branch
  }

  float dinv[5]; float wsum = 0.f;
#pragma unroll
  for (int k = 0; k < 5; ++k) {
    dinv[k] = 1.0f / sqrtf(s5[k] + EPS_);
    wsum += dinv[k];
  }
  if (lane < OUT_) {
    float acc = 0.f;
#pragma unroll
    for (int k = 0; k < 5; ++k)
      acc = fmaf(dinv[k] / wsum, ty[(size_t)id5[k] * OUT_ + lane], acc);
    out[(size_t)q * OUT_ + lane] = acc;
  }
}

// ---------------------------------------------------------------------------
extern "C" void kernel_launch(void* const* d_in, const int* in_sizes, int n_in,
                              void* d_out, int out_size, void* d_ws, size_t ws_size,
                              hipStream_t stream) {
  const float* x   = (const float*)d_in[0];
  const float* tx  = (const float*)d_in[1];
  const float* ty  = (const float*)d_in[2];
  const float* wts = (const float*)d_in[3];
  float* out = (float*)d_out;

  char* ws = (char*)d_ws;
  size_t off = 0;
  float* xqs = (float*)(ws + off); off += (size_t)N_Q * D_ * 4;      // 512KB
  float* xts = (float*)(ws + off); off += (size_t)M_T * D_ * 4;      // 2MB
  float* xqn = (float*)(ws + off); off += (size_t)N_Q * 4;
  float* xtn = (float*)(ws + off); off += (size_t)M_T * 4;
  unsigned short* xq_h = (unsigned short*)(ws + off); off += (size_t)N_Q * D_ * 2;
  unsigned short* xq_l = (unsigned short*)(ws + off); off += (size_t)N_Q * D_ * 2;
  unsigned short* xt_h = (unsigned short*)(ws + off); off += (size_t)M_T * D_ * 2;
  unsigned int* pkey = (unsigned int*)(ws + off);                    // 2.6MB

  p0_prep<<<dim3((N_Q + M_T) * 4 / 256), dim3(256), 0, stream>>>(
      x, tx, wts, xqs, xts, xqn, xtn, xq_h, xq_l, xt_h);
  p1_topk<<<dim3(NCHUNK, N_Q / 64), dim3(256), 0, stream>>>(
      xq_h, xq_l, xt_h, xtn, pkey);
  p2_merge<<<dim3(N_Q * 64 / 256), dim3(256), 0, stream>>>(
      pkey, xqs, xqn, xts, xtn, ty, out);
}